// Round 20
// baseline (78.140 us; speedup 1.0000x reference)
//
#include <hip/hip_runtime.h>
#include <math.h>

namespace {
constexpr int B_ = 32, P_ = 8192, G_ = 150, C_ = 8;
constexpr int TG = 10;                 // gts per block in cost kernel
constexpr int NTILE = G_ / TG;         // 15
constexpr int PCH = 16;                // P chunks in cost kernel
constexpr int PCHUNK = P_ / PCH;       // 512
constexpr int NXCD = 8;                // XCDs on MI355X
constexpr int LT = 1024;               // k_losses block size (16 waves)
constexpr float ALPHA_ = 0.25f;
constexpr float THRESH_ = 1.5f;
constexpr float EPS_ = 1e-6f;
constexpr float LOG2E_ = 1.44269504088896340736f;
constexpr float LN2_   = 0.69314718055994530942f;
constexpr float HSQ2_ = 0.70710678118654752440f;   // 0.5*sqrt(2)
}

__device__ __forceinline__ float rcp_f(float x) { return __builtin_amdgcn_rcpf(x); }
__device__ __forceinline__ float rfl_f(float x) {
    return __int_as_float(__builtin_amdgcn_readfirstlane(__float_as_int(x)));
}

// precise giou for the loss terms (matches reference op order)
__device__ __forceinline__ float giou_f(const float4 b1, const float4 b2) {
    float a1 = (b1.z - b1.x) * (b1.w - b1.y);
    float a2 = (b2.z - b2.x) * (b2.w - b2.y);
    float iw = fmaxf(fminf(b1.z, b2.z) - fmaxf(b1.x, b2.x), 0.0f);
    float ih = fmaxf(fminf(b1.w, b2.w) - fmaxf(b1.y, b2.y), 0.0f);
    float inter = iw * ih;
    float uni = a1 + a2 - inter;
    float iou = inter / (uni + EPS_);
    float enc = (fmaxf(b1.z, b2.z) - fminf(b1.x, b2.x)) *
                (fmaxf(b1.w, b2.w) - fminf(b1.y, b2.y));
    return iou - (enc - uni) / (enc + EPS_);
}

// ---------------------------------------------------------------------------
// block-wide deterministic sum (LT = 1024 threads, 16 waves)
// ---------------------------------------------------------------------------
__device__ __forceinline__ float block_sum1024(float v, const int tid) {
    __shared__ float tmp[LT / 64];
    for (int off = 32; off; off >>= 1) v += __shfl_down(v, off, 64);
    if ((tid & 63) == 0) tmp[tid >> 6] = v;
    __syncthreads();
    float r = 0.0f;
#pragma unroll
    for (int i = 0; i < LT / 64; ++i) r += tmp[i];
    __syncthreads();
    return r;
}

// ---------------------------------------------------------------------------
// Kernel 1: single-wave blocks (64 threads), 1D grid, XCD-aware decode.
// R18 body + enc via max+min identity (reuses iwr/ihr; saves 2 VALU per
// pair-dim).  Grid caps waves/SIMD (~4), so the small VGPR increase from
// pw/ph/gw/gh cannot reduce occupancy (safe re-isolation of R7's change).
// ---------------------------------------------------------------------------
__global__ __launch_bounds__(64) void k_cost_min(
    const float* __restrict__ pbox,   // [B,P,4]
    const float* __restrict__ plog,   // [B,P,C]
    const float* __restrict__ gbox,   // [B,G,4]
    const int*   __restrict__ glbl,   // [B,G]
    const int*   __restrict__ nobj,   // [B]
    float* __restrict__ out_minc,     // [B,G,PCH]
    int*   __restrict__ out_assig,    // [B,G,PCH]
    int*   __restrict__ cnt)
{
    if (blockIdx.x == 0 && threadIdx.x == 0) *cnt = 0;

    // decode: bid = xcd + NXCD*(tile + NTILE*grp); pair = xcd + NXCD*grp
    const int bid  = blockIdx.x;
    const int xcd  = bid & (NXCD - 1);
    const int t2   = bid >> 3;            // NXCD == 8
    const int tile = t2 % NTILE;
    const int grp  = t2 / NTILE;
    const int pair = xcd + NXCD * grp;    // 0 .. PCH*B-1
    const int ch   = pair & (PCH - 1);    // PCH == 16
    const int b    = pair >> 4;
    const int g0   = tile * TG;
    if (g0 >= nobj[b]) return;        // dead gt-tile: results never consumed

    const int tid = threadIdx.x;      // 0..63 (one wave)
    const int p0  = ch * PCHUNK;

    __shared__ float sw[64][9];       // per-thread premultiplied -0.5*probs

    // wave-uniform gt fields -> SGPRs
    float gx1[TG], gy1[TG], gx2[TG], gy2[TG], gcx[TG], gcy[TG];
    float gar[TG], gw[TG], gh[TG];
    int gL[TG];
    {
        const float4* gb4 = (const float4*)(gbox + ((size_t)b * G_ + g0) * 4);
        const int* gl = glbl + b * G_ + g0;
#pragma unroll
        for (int j = 0; j < TG; ++j) {
            const float4 gb = gb4[j];
            gx1[j] = rfl_f(gb.x); gy1[j] = rfl_f(gb.y);
            gx2[j] = rfl_f(gb.z); gy2[j] = rfl_f(gb.w);
            gcx[j] = rfl_f((gb.x + gb.z) * HSQ2_);
            gcy[j] = rfl_f((gb.y + gb.w) * HSQ2_);
            gw[j]  = rfl_f(gb.z - gb.x);
            gh[j]  = rfl_f(gb.w - gb.y);
            gar[j] = rfl_f((gb.z - gb.x) * (gb.w - gb.y));
            gL[j]  = __builtin_amdgcn_readfirstlane(gl[j]);
        }
    }

    float bc[TG]; int bi[TG];
#pragma unroll
    for (int j = 0; j < TG; ++j) { bc[j] = INFINITY; bi[j] = 0; }

    const float4* pb4 = (const float4*)(pbox + (size_t)b * P_ * 4);
    const float4* pl4 = (const float4*)(plog + (size_t)b * P_ * C_);

    for (int p = p0 + tid; p < p0 + PCHUNK; p += 64) {
        const float4 pb = pb4[p];
        const float4 l0 = pl4[2 * p];
        const float4 l1 = pl4[2 * p + 1];
        const float pcx = (pb.x + pb.z) * HSQ2_;
        const float pcy = (pb.y + pb.w) * HSQ2_;
        const float pw  = pb.z - pb.x;
        const float ph  = pb.w - pb.y;
        const float a1  = pw * ph;

        const float m = fmaxf(fmaxf(fmaxf(l0.x, l0.y), fmaxf(l0.z, l0.w)),
                              fmaxf(fmaxf(l1.x, l1.y), fmaxf(l1.z, l1.w)));
        const float mm = -m * LOG2E_;
        const float e0 = __builtin_amdgcn_exp2f(fmaf(l0.x, LOG2E_, mm));
        const float e1 = __builtin_amdgcn_exp2f(fmaf(l0.y, LOG2E_, mm));
        const float e2 = __builtin_amdgcn_exp2f(fmaf(l0.z, LOG2E_, mm));
        const float e3 = __builtin_amdgcn_exp2f(fmaf(l0.w, LOG2E_, mm));
        const float e4 = __builtin_amdgcn_exp2f(fmaf(l1.x, LOG2E_, mm));
        const float e5 = __builtin_amdgcn_exp2f(fmaf(l1.y, LOG2E_, mm));
        const float e6 = __builtin_amdgcn_exp2f(fmaf(l1.z, LOG2E_, mm));
        const float e7 = __builtin_amdgcn_exp2f(fmaf(l1.w, LOG2E_, mm));
        const float se = ((e0 + e1) + (e2 + e3)) + ((e4 + e5) + (e6 + e7));
        const float s  = -0.5f * rcp_f(se);     // fold COST_W_CLS and the minus
        sw[tid][0] = e0 * s; sw[tid][1] = e1 * s; sw[tid][2] = e2 * s; sw[tid][3] = e3 * s;
        sw[tid][4] = e4 * s; sw[tid][5] = e5 * s; sw[tid][6] = e6 * s; sw[tid][7] = e7 * s;

#pragma unroll
        for (int j = 0; j < TG; ++j) {
            // distance: centers pre-scaled by sqrt2 -> sqrt(d2) == 2*nd
            const float dx = pcx - gcx[j], dy = pcy - gcy[j];
            const float d2 = fmaf(dx, dx, dy * dy);
            const float sd = __builtin_amdgcn_sqrtf(d2);

            const float iwr = fminf(pb.z, gx2[j]) - fmaxf(pb.x, gx1[j]);
            const float ihr = fminf(pb.w, gy2[j]) - fmaxf(pb.y, gy1[j]);
            const float inter = fmaxf(iwr, 0.0f) * fmaxf(ihr, 0.0f);
            const float uni = (a1 + gar[j]) - inter;
            // enclosing box via max+min identity (reuses iwr/ihr)
            const float encw = (pw + gw[j]) - iwr;
            const float ench = (ph + gh[j]) - ihr;
            const float enc  = encw * ench;
            // c0 = (enc-uni)/(enc+EPS) - inter/(uni+EPS), with a single rcp:
            const float x = uni + EPS_;
            const float y = enc + EPS_;
            const float r = rcp_f(x * y);
            const float num = fmaf(enc - uni, x, -(inter * y));
            const float c0 = num * r;
            const float cost = sd + (c0 + sw[tid][gL[j]]);
            // strict < keeps first (lowest p) on ties; p increases per thread
            if (cost < bc[j]) { bc[j] = cost; bi[j] = p; }
        }
    }

    // wave reduce: min cost, tie -> lowest pred index; lane 0 stores
#pragma unroll
    for (int j = 0; j < TG; ++j) {
        float c = bc[j]; int i = bi[j];
        for (int off = 32; off; off >>= 1) {
            const float c2 = __shfl_down(c, off, 64);
            const int   i2 = __shfl_down(i, off, 64);
            if (c2 < c || (c2 == c && i2 < i)) { c = c2; i = i2; }
        }
        if (tid == 0) {
            out_minc[(b * G_ + g0 + j) * PCH + ch]  = c;
            out_assig[(b * G_ + g0 + j) * PCH + ch] = i;
        }
    }
}

// ---------------------------------------------------------------------------
// Kernel 2: per-image tail, 32 blocks x 1024 threads (16 waves).
// Focal background fused here (float4 loads, 2 iterations), then chunk-merge
// + conflict resolution + all loss terms.
// Last block performs the final cross-image combine (threadfence + counter).
// ---------------------------------------------------------------------------
__global__ __launch_bounds__(LT) void k_losses(
    const float* __restrict__ obj,    // [B,P]
    const float* __restrict__ pbox,   // [B,P,4]
    const float* __restrict__ plog,   // [B,P,C]
    const float* __restrict__ gbox,   // [B,G,4]
    const int*   __restrict__ glbl,   // [B,G]
    const int*   __restrict__ nobj,   // [B]
    const float* __restrict__ pminc,  // [B,G,PCH]
    const int*   __restrict__ passig, // [B,G,PCH]
    float* __restrict__ img,          // [B,4]: obj, bbox, class, n_m
    int* __restrict__ cnt,
    float* __restrict__ out)          // [4]
{
    const int b = blockIdx.x, tid = threadIdx.x;
    __shared__ float s_c[G_];
    __shared__ int   s_p[G_];
    __shared__ unsigned char s_valid[G_], s_win[G_];
    __shared__ int s_wp[G_], s_wg[G_], s_nw;
    __shared__ int s_last;

    const int n = nobj[b];
    if (tid < G_) {
        // merge the PCH partial (min, argmin); ascending chunk = ascending p
        // (entries for tid >= n are stale/poison but provably never used)
        float c = INFINITY; int i = 0x7fffffff;
        const float* pc = pminc  + (size_t)(b * G_ + tid) * PCH;
        const int*   pi = passig + (size_t)(b * G_ + tid) * PCH;
#pragma unroll
        for (int ch = 0; ch < PCH; ++ch) {
            const float c2 = pc[ch]; const int i2 = pi[ch];
            if (c2 < c || (c2 == c && i2 < i)) { c = c2; i = i2; }
        }
        s_c[tid] = c;
        s_p[tid] = i;
        s_valid[tid] = (c < THRESH_) && (tid < n);
    }
    __syncthreads();

    // winner: for each valid gt, is it the best (lowest cost, tie -> lowest g)
    // among valid gts assigned to the same pred?
    if (tid < G_) {
        unsigned char w = 0;
        if (s_valid[tid]) {
            w = 1;
            const int p = s_p[tid]; const float c = s_c[tid];
            for (int g2 = 0; g2 < G_; ++g2) {
                if (g2 == tid || !s_valid[g2] || s_p[g2] != p) continue;
                const float c2 = s_c[g2];
                if (c2 < c || (c2 == c && g2 < tid)) { w = 0; break; }
            }
        }
        s_win[tid] = w;
    }
    __syncthreads();
    if (tid == 0) {
        int nw = 0;
        for (int g = 0; g < G_; ++g) nw += s_win[g];
        s_nw = nw;
    }
    if (tid < G_ && s_win[tid]) {   // deterministic compaction via prefix count
        int slot = 0;
        for (int g2 = 0; g2 < tid; ++g2) slot += s_win[g2];
        s_wp[slot] = s_p[tid];
        s_wg[slot] = tid;
    }
    __syncthreads();
    const int nw = s_nw;

    // focal objectness: full background sum, float4-vectorized (2 iterations)
    const float* ob = obj + (size_t)b * P_;
    const float4* ob4 = (const float4*)ob;
    float fsum = 0.0f;
#pragma unroll
    for (int k = 0; k < P_ / (LT * 4); ++k) {
        const float4 v4 = ob4[tid + k * LT];
        const float vs[4] = {v4.x, v4.y, v4.z, v4.w};
#pragma unroll
        for (int u = 0; u < 4; ++u) {
            float v = fminf(fmaxf(vs[u], 1e-7f), 1.0f - 1e-7f);
            const float nl = -__builtin_amdgcn_logf(1.0f - v) * LN2_;
            fsum += ALPHA_ * v * v * nl;
        }
    }

    float gsum = 0.0f, asum = 0.0f, csum = 0.0f;
    if (tid < nw) {
        const int p = s_wp[tid], g = s_wg[tid];
        float v = ob[p];
        v = fminf(fmaxf(v, 1e-7f), 1.0f - 1e-7f);
        const float nl1 = -__builtin_amdgcn_logf(1.0f - v) * LN2_;  // matches bg term
        fsum += ALPHA_ * (1.0f - v) * (1.0f - v) * (-logf(v))
              - ALPHA_ * v * v * nl1;

        const float4 pb = *(const float4*)(pbox + ((size_t)b * P_ + p) * 4);
        const float4 gb = *(const float4*)(gbox + ((size_t)b * G_ + g) * 4);
        gsum = 1.0f - giou_f(pb, gb);

        const float pa = (pb.z - pb.x) / (pb.w - pb.y + EPS_);
        const float ga = (gb.z - gb.x) / (gb.w - gb.y + EPS_);
        const float da = fabsf(pa - ga);
        asum = (da < 1.0f) ? 0.5f * da * da : (da - 0.5f);

        const float* lg = plog + ((size_t)b * P_ + p) * C_;
        const float l0 = lg[0], l1 = lg[1], l2 = lg[2], l3 = lg[3];
        const float l4 = lg[4], l5 = lg[5], l6 = lg[6], l7 = lg[7];
        const float m = fmaxf(fmaxf(fmaxf(l0, l1), fmaxf(l2, l3)),
                              fmaxf(fmaxf(l4, l5), fmaxf(l6, l7)));
        const float se = expf(l0 - m) + expf(l1 - m) + expf(l2 - m) + expf(l3 - m)
                       + expf(l4 - m) + expf(l5 - m) + expf(l6 - m) + expf(l7 - m);
        const int L = glbl[b * G_ + g];
        const float lL = lg[L];
        csum = -(lL - m - logf(se));
    }

    const float ft  = block_sum1024(fsum, tid);
    const float gt_ = block_sum1024(gsum, tid);
    const float at  = block_sum1024(asum, tid);
    const float ct  = block_sum1024(csum, tid);

    if (tid == 0) {
        const float denom = fmaxf((float)nw, 1.0f);
        img[b * 4 + 0] = ft / (float)P_;                 // obj_loss (mean)
        img[b * 4 + 1] = gt_ / denom + at / denom;       // giou + aspect
        img[b * 4 + 2] = ct / denom;                     // class
        img[b * 4 + 3] = (float)nw;                      // n_m
        __threadfence();
        const int old = atomicAdd(cnt, 1);
        s_last = (old == B_ - 1);
    }
    __syncthreads();
    if (tid == 0 && s_last) {
        __threadfence();
        float so = 0.f, sbb = 0.f, scl = 0.f, snm = 0.f;
        for (int bb2 = 0; bb2 < B_; ++bb2) {
            so  += img[bb2 * 4 + 0];
            sbb += img[bb2 * 4 + 1];
            scl += img[bb2 * 4 + 2];
            snm += img[bb2 * 4 + 3];
        }
        const float denom = fmaxf(snm, 1.0f);
        const float o  = so / (float)B_;
        const float bb = sbb / denom;
        const float cl = scl / denom;
        out[0] = o + bb + cl;
        out[1] = o;
        out[2] = bb;
        out[3] = cl;
        *cnt = 0;
    }
}

extern "C" void kernel_launch(void* const* d_in, const int* in_sizes, int n_in,
                              void* d_out, int out_size, void* d_ws, size_t ws_size,
                              hipStream_t stream) {
    const float* obj  = (const float*)d_in[0];   // [B,P]
    const float* pbox = (const float*)d_in[1];   // [B,P,4]
    const float* plog = (const float*)d_in[2];   // [B,P,C]
    const float* gbox = (const float*)d_in[3];   // [B,G,4]
    const int*   glbl = (const int*)d_in[4];     // [B,G]
    const int*   nobj = (const int*)d_in[5];     // [B]
    float* out = (float*)d_out;

    char* ws = (char*)d_ws;
    size_t off = 0;
    float* pminc  = (float*)(ws + off); off += (size_t)B_ * G_ * PCH * 4;
    int*   passig = (int*)  (ws + off); off += (size_t)B_ * G_ * PCH * 4;
    float* img    = (float*)(ws + off); off += (size_t)B_ * 4 * 4;
    int*   cnt    = (int*)  (ws + off); off += 64;

    k_cost_min<<<dim3(NTILE * PCH * B_), 64, 0, stream>>>(pbox, plog, gbox, glbl,
                                                          nobj, pminc, passig, cnt);
    k_losses<<<dim3(B_), LT, 0, stream>>>(obj, pbox, plog, gbox, glbl, nobj,
                                          pminc, passig, img, cnt, out);
}

// Round 21
// 62.241 us; speedup vs baseline: 1.2554x; 1.2554x over previous
//
#include <hip/hip_runtime.h>
#include <math.h>

namespace {
constexpr int B_ = 32, P_ = 8192, G_ = 150, C_ = 8;
constexpr int TG = 10;                 // gts per block in cost kernel
constexpr int NTILE = G_ / TG;         // 15
constexpr int PCH = 16;                // P chunks in cost kernel
constexpr int PCHUNK = P_ / PCH;       // 512
constexpr int NXCD = 8;                // XCDs on MI355X
constexpr int LT = 512;                // k_losses block size (8 waves)
constexpr float ALPHA_ = 0.25f;
constexpr float THRESH_ = 1.5f;
constexpr float EPS_ = 1e-6f;
constexpr float LOG2E_ = 1.44269504088896340736f;
constexpr float LN2_   = 0.69314718055994530942f;
constexpr float HSQ2_ = 0.70710678118654752440f;   // 0.5*sqrt(2)
}

__device__ __forceinline__ float rcp_f(float x) { return __builtin_amdgcn_rcpf(x); }
__device__ __forceinline__ float rfl_f(float x) {
    return __int_as_float(__builtin_amdgcn_readfirstlane(__float_as_int(x)));
}

// precise giou for the loss terms (matches reference op order)
__device__ __forceinline__ float giou_f(const float4 b1, const float4 b2) {
    float a1 = (b1.z - b1.x) * (b1.w - b1.y);
    float a2 = (b2.z - b2.x) * (b2.w - b2.y);
    float iw = fmaxf(fminf(b1.z, b2.z) - fmaxf(b1.x, b2.x), 0.0f);
    float ih = fmaxf(fminf(b1.w, b2.w) - fmaxf(b1.y, b2.y), 0.0f);
    float inter = iw * ih;
    float uni = a1 + a2 - inter;
    float iou = inter / (uni + EPS_);
    float enc = (fmaxf(b1.z, b2.z) - fminf(b1.x, b2.x)) *
                (fmaxf(b1.w, b2.w) - fminf(b1.y, b2.y));
    return iou - (enc - uni) / (enc + EPS_);
}

// ---------------------------------------------------------------------------
// fused 4-value block sum for LT=512 threads (one barrier)
// ---------------------------------------------------------------------------
__device__ __forceinline__ float4 block_sum4(float4 v, const int tid) {
    __shared__ float tmp[LT / 64][4];
    for (int o = 32; o; o >>= 1) {
        v.x += __shfl_down(v.x, o, 64);
        v.y += __shfl_down(v.y, o, 64);
        v.z += __shfl_down(v.z, o, 64);
        v.w += __shfl_down(v.w, o, 64);
    }
    const int wv = tid >> 6;
    if ((tid & 63) == 0) {
        tmp[wv][0] = v.x; tmp[wv][1] = v.y; tmp[wv][2] = v.z; tmp[wv][3] = v.w;
    }
    __syncthreads();
    float4 r = make_float4(0.f, 0.f, 0.f, 0.f);
#pragma unroll
    for (int i = 0; i < LT / 64; ++i) {
        r.x += tmp[i][0]; r.y += tmp[i][1]; r.z += tmp[i][2]; r.w += tmp[i][3];
    }
    return r;
}

// ---------------------------------------------------------------------------
// Kernel 1: single-wave blocks (64 threads), 1D grid, XCD-aware decode
// (R16/R18 champion body VERBATIM — frozen).  Block 0 zeroes cnt.
// ---------------------------------------------------------------------------
__global__ __launch_bounds__(64) void k_cost_min(
    const float* __restrict__ pbox,   // [B,P,4]
    const float* __restrict__ plog,   // [B,P,C]
    const float* __restrict__ gbox,   // [B,G,4]
    const int*   __restrict__ glbl,   // [B,G]
    const int*   __restrict__ nobj,   // [B]
    float* __restrict__ out_minc,     // [B,G,PCH]
    int*   __restrict__ out_assig,    // [B,G,PCH]
    int*   __restrict__ cnt)
{
    if (blockIdx.x == 0 && threadIdx.x == 0) *cnt = 0;

    // decode: bid = xcd + NXCD*(tile + NTILE*grp); pair = xcd + NXCD*grp
    const int bid  = blockIdx.x;
    const int xcd  = bid & (NXCD - 1);
    const int t2   = bid >> 3;            // NXCD == 8
    const int tile = t2 % NTILE;
    const int grp  = t2 / NTILE;
    const int pair = xcd + NXCD * grp;    // 0 .. PCH*B-1
    const int ch   = pair & (PCH - 1);    // PCH == 16
    const int b    = pair >> 4;
    const int g0   = tile * TG;
    if (g0 >= nobj[b]) return;        // dead gt-tile: results never consumed

    const int tid = threadIdx.x;      // 0..63 (one wave)
    const int p0  = ch * PCHUNK;

    __shared__ float sw[64][9];       // per-thread premultiplied -0.5*probs

    // wave-uniform gt fields -> SGPRs
    float gx1[TG], gy1[TG], gx2[TG], gy2[TG], gcx[TG], gcy[TG], gar[TG];
    int gL[TG];
    {
        const float4* gb4 = (const float4*)(gbox + ((size_t)b * G_ + g0) * 4);
        const int* gl = glbl + b * G_ + g0;
#pragma unroll
        for (int j = 0; j < TG; ++j) {
            const float4 gb = gb4[j];
            gx1[j] = rfl_f(gb.x); gy1[j] = rfl_f(gb.y);
            gx2[j] = rfl_f(gb.z); gy2[j] = rfl_f(gb.w);
            gcx[j] = rfl_f((gb.x + gb.z) * HSQ2_);
            gcy[j] = rfl_f((gb.y + gb.w) * HSQ2_);
            gar[j] = rfl_f((gb.z - gb.x) * (gb.w - gb.y));
            gL[j]  = __builtin_amdgcn_readfirstlane(gl[j]);
        }
    }

    float bc[TG]; int bi[TG];
#pragma unroll
    for (int j = 0; j < TG; ++j) { bc[j] = INFINITY; bi[j] = 0; }

    const float4* pb4 = (const float4*)(pbox + (size_t)b * P_ * 4);
    const float4* pl4 = (const float4*)(plog + (size_t)b * P_ * C_);

    for (int p = p0 + tid; p < p0 + PCHUNK; p += 64) {
        const float4 pb = pb4[p];
        const float4 l0 = pl4[2 * p];
        const float4 l1 = pl4[2 * p + 1];
        const float pcx = (pb.x + pb.z) * HSQ2_;
        const float pcy = (pb.y + pb.w) * HSQ2_;
        const float a1  = (pb.z - pb.x) * (pb.w - pb.y);

        const float m = fmaxf(fmaxf(fmaxf(l0.x, l0.y), fmaxf(l0.z, l0.w)),
                              fmaxf(fmaxf(l1.x, l1.y), fmaxf(l1.z, l1.w)));
        const float mm = -m * LOG2E_;
        const float e0 = __builtin_amdgcn_exp2f(fmaf(l0.x, LOG2E_, mm));
        const float e1 = __builtin_amdgcn_exp2f(fmaf(l0.y, LOG2E_, mm));
        const float e2 = __builtin_amdgcn_exp2f(fmaf(l0.z, LOG2E_, mm));
        const float e3 = __builtin_amdgcn_exp2f(fmaf(l0.w, LOG2E_, mm));
        const float e4 = __builtin_amdgcn_exp2f(fmaf(l1.x, LOG2E_, mm));
        const float e5 = __builtin_amdgcn_exp2f(fmaf(l1.y, LOG2E_, mm));
        const float e6 = __builtin_amdgcn_exp2f(fmaf(l1.z, LOG2E_, mm));
        const float e7 = __builtin_amdgcn_exp2f(fmaf(l1.w, LOG2E_, mm));
        const float se = ((e0 + e1) + (e2 + e3)) + ((e4 + e5) + (e6 + e7));
        const float s  = -0.5f * rcp_f(se);     // fold COST_W_CLS and the minus
        sw[tid][0] = e0 * s; sw[tid][1] = e1 * s; sw[tid][2] = e2 * s; sw[tid][3] = e3 * s;
        sw[tid][4] = e4 * s; sw[tid][5] = e5 * s; sw[tid][6] = e6 * s; sw[tid][7] = e7 * s;

#pragma unroll
        for (int j = 0; j < TG; ++j) {
            // distance: centers pre-scaled by sqrt2 -> sqrt(d2) == 2*nd
            const float dx = pcx - gcx[j], dy = pcy - gcy[j];
            const float d2 = fmaf(dx, dx, dy * dy);
            const float sd = __builtin_amdgcn_sqrtf(d2);

            const float iwr = fminf(pb.z, gx2[j]) - fmaxf(pb.x, gx1[j]);
            const float ihr = fminf(pb.w, gy2[j]) - fmaxf(pb.y, gy1[j]);
            const float inter = fmaxf(iwr, 0.0f) * fmaxf(ihr, 0.0f);
            const float uni = (a1 + gar[j]) - inter;
            const float encw = (fmaxf(pb.z, gx2[j]) - fminf(pb.x, gx1[j]));
            const float ench = (fmaxf(pb.w, gy2[j]) - fminf(pb.y, gy1[j]));
            const float enc  = encw * ench;
            // c0 = (enc-uni)/(enc+EPS) - inter/(uni+EPS), with a single rcp:
            const float x = uni + EPS_;
            const float y = enc + EPS_;
            const float r = rcp_f(x * y);
            const float num = fmaf(enc - uni, x, -(inter * y));
            const float c0 = num * r;
            const float cost = sd + (c0 + sw[tid][gL[j]]);
            // strict < keeps first (lowest p) on ties; p increases per thread
            if (cost < bc[j]) { bc[j] = cost; bi[j] = p; }
        }
    }

    // wave reduce: min cost, tie -> lowest pred index; lane 0 stores
#pragma unroll
    for (int j = 0; j < TG; ++j) {
        float c = bc[j]; int i = bi[j];
        for (int off = 32; off; off >>= 1) {
            const float c2 = __shfl_down(c, off, 64);
            const int   i2 = __shfl_down(i, off, 64);
            if (c2 < c || (c2 == c && i2 < i)) { c = c2; i = i2; }
        }
        if (tid == 0) {
            out_minc[(b * G_ + g0 + j) * PCH + ch]  = c;
            out_assig[(b * G_ + g0 + j) * PCH + ch] = i;
        }
    }
}

// ---------------------------------------------------------------------------
// Kernel 2: per-image tail, 32 blocks x 512 threads (8 waves).
//  * winner detection parallelized 8-way over g2-slices (same boolean result)
//  * compaction via 5-word bitmask + popcount (same ascending-g slot order)
//  * focal fused, float4 loads; single fused 4-value reduction
// Last block performs the final cross-image combine (threadfence + counter).
// ---------------------------------------------------------------------------
__global__ __launch_bounds__(LT) void k_losses(
    const float* __restrict__ obj,    // [B,P]
    const float* __restrict__ pbox,   // [B,P,4]
    const float* __restrict__ plog,   // [B,P,C]
    const float* __restrict__ gbox,   // [B,G,4]
    const int*   __restrict__ glbl,   // [B,G]
    const int*   __restrict__ nobj,   // [B]
    const float* __restrict__ pminc,  // [B,G,PCH]
    const int*   __restrict__ passig, // [B,G,PCH]
    float* __restrict__ img,          // [B,4]: obj, bbox, class, n_m
    int* __restrict__ cnt,
    float* __restrict__ out)          // [4]
{
    const int b = blockIdx.x, tid = threadIdx.x;
    __shared__ float s_c[G_];
    __shared__ int   s_p[G_];
    __shared__ unsigned char s_valid[G_], s_beat[G_];
    __shared__ unsigned int s_winm[5];
    __shared__ int s_wp[G_], s_wg[G_], s_nw;
    __shared__ int s_last;

    const int n = nobj[b];
    if (tid < 5) s_winm[tid] = 0;
    if (tid < G_) {
        s_beat[tid] = 0;
        // merge the PCH partial (min, argmin); ascending chunk = ascending p
        float c = INFINITY; int i = 0x7fffffff;
        const float* pc = pminc  + (size_t)(b * G_ + tid) * PCH;
        const int*   pi = passig + (size_t)(b * G_ + tid) * PCH;
#pragma unroll
        for (int ch = 0; ch < PCH; ++ch) {
            const float c2 = pc[ch]; const int i2 = pi[ch];
            if (c2 < c || (c2 == c && i2 < i)) { c = c2; i = i2; }
        }
        s_c[tid] = c;
        s_p[tid] = i;
        s_valid[tid] = (c < THRESH_) && (tid < n);
    }
    __syncthreads();

    // winner detection, 8 slices of g2 per g (1200 work items):
    // g is beaten if a valid same-pred g2 has lower cost (tie -> lower g).
    for (int t = tid; t < G_ * 8; t += LT) {
        const int g  = t >> 3;
        const int sl = t & 7;
        if (!s_valid[g]) continue;
        const int p = s_p[g]; const float c = s_c[g];
        const int g2e = min(sl * 19 + 19, G_);
        for (int g2 = sl * 19; g2 < g2e; ++g2) {
            if (g2 == g || !s_valid[g2] || s_p[g2] != p) continue;
            const float c2 = s_c[g2];
            if (c2 < c || (c2 == c && g2 < g)) { s_beat[g] = 1; break; }
        }
    }
    __syncthreads();

    // winner bitmask
    if (tid < G_) {
        if (s_valid[tid] && !s_beat[tid])
            atomicOr(&s_winm[tid >> 5], 1u << (tid & 31));
    }
    __syncthreads();

    // count + compaction via popcount (ascending-g slot order preserved)
    if (tid == 0) {
        int nw = 0;
#pragma unroll
        for (int w2 = 0; w2 < 5; ++w2) nw += __popc(s_winm[w2]);
        s_nw = nw;
    }
    if (tid < G_ && s_valid[tid] && !s_beat[tid]) {
        const int word = tid >> 5, bit = tid & 31;
        int slot = __popc(s_winm[word] & ((1u << bit) - 1));
#pragma unroll
        for (int w2 = 0; w2 < 4; ++w2)
            if (w2 < word) slot += __popc(s_winm[w2]);
        s_wp[slot] = s_p[tid];
        s_wg[slot] = tid;
    }
    __syncthreads();
    const int nw = s_nw;

    // focal objectness: full background sum, float4-vectorized
    const float* ob = obj + (size_t)b * P_;
    const float4* ob4 = (const float4*)ob;
    float fsum = 0.0f;
#pragma unroll
    for (int k = 0; k < P_ / (LT * 4); ++k) {
        const float4 v4 = ob4[tid + k * LT];
        const float vs[4] = {v4.x, v4.y, v4.z, v4.w};
#pragma unroll
        for (int u = 0; u < 4; ++u) {
            float v = fminf(fmaxf(vs[u], 1e-7f), 1.0f - 1e-7f);
            const float nl = -__builtin_amdgcn_logf(1.0f - v) * LN2_;
            fsum += ALPHA_ * v * v * nl;
        }
    }

    float gsum = 0.0f, asum = 0.0f, csum = 0.0f;
    if (tid < nw) {
        const int p = s_wp[tid], g = s_wg[tid];
        float v = ob[p];
        v = fminf(fmaxf(v, 1e-7f), 1.0f - 1e-7f);
        const float nl1 = -__builtin_amdgcn_logf(1.0f - v) * LN2_;  // matches bg term
        fsum += ALPHA_ * (1.0f - v) * (1.0f - v) * (-logf(v))
              - ALPHA_ * v * v * nl1;

        const float4 pb = *(const float4*)(pbox + ((size_t)b * P_ + p) * 4);
        const float4 gb = *(const float4*)(gbox + ((size_t)b * G_ + g) * 4);
        gsum = 1.0f - giou_f(pb, gb);

        const float pa = (pb.z - pb.x) / (pb.w - pb.y + EPS_);
        const float ga = (gb.z - gb.x) / (gb.w - gb.y + EPS_);
        const float da = fabsf(pa - ga);
        asum = (da < 1.0f) ? 0.5f * da * da : (da - 0.5f);

        const float* lg = plog + ((size_t)b * P_ + p) * C_;
        const float l0 = lg[0], l1 = lg[1], l2 = lg[2], l3 = lg[3];
        const float l4 = lg[4], l5 = lg[5], l6 = lg[6], l7 = lg[7];
        const float m = fmaxf(fmaxf(fmaxf(l0, l1), fmaxf(l2, l3)),
                              fmaxf(fmaxf(l4, l5), fmaxf(l6, l7)));
        const float se = expf(l0 - m) + expf(l1 - m) + expf(l2 - m) + expf(l3 - m)
                       + expf(l4 - m) + expf(l5 - m) + expf(l6 - m) + expf(l7 - m);
        const int L = glbl[b * G_ + g];
        const float lL = lg[L];
        csum = -(lL - m - logf(se));
    }

    const float4 tot = block_sum4(make_float4(fsum, gsum, asum, csum), tid);

    if (tid == 0) {
        const float denom = fmaxf((float)nw, 1.0f);
        img[b * 4 + 0] = tot.x / (float)P_;              // obj_loss (mean)
        img[b * 4 + 1] = tot.y / denom + tot.z / denom;  // giou + aspect
        img[b * 4 + 2] = tot.w / denom;                  // class
        img[b * 4 + 3] = (float)nw;                      // n_m
        __threadfence();
        const int old = atomicAdd(cnt, 1);
        s_last = (old == B_ - 1);
    }
    __syncthreads();
    if (tid == 0 && s_last) {
        __threadfence();
        float so = 0.f, sbb = 0.f, scl = 0.f, snm = 0.f;
        for (int bb2 = 0; bb2 < B_; ++bb2) {
            so  += img[bb2 * 4 + 0];
            sbb += img[bb2 * 4 + 1];
            scl += img[bb2 * 4 + 2];
            snm += img[bb2 * 4 + 3];
        }
        const float denom = fmaxf(snm, 1.0f);
        const float o  = so / (float)B_;
        const float bb = sbb / denom;
        const float cl = scl / denom;
        out[0] = o + bb + cl;
        out[1] = o;
        out[2] = bb;
        out[3] = cl;
        *cnt = 0;
    }
}

extern "C" void kernel_launch(void* const* d_in, const int* in_sizes, int n_in,
                              void* d_out, int out_size, void* d_ws, size_t ws_size,
                              hipStream_t stream) {
    const float* obj  = (const float*)d_in[0];   // [B,P]
    const float* pbox = (const float*)d_in[1];   // [B,P,4]
    const float* plog = (const float*)d_in[2];   // [B,P,C]
    const float* gbox = (const float*)d_in[3];   // [B,G,4]
    const int*   glbl = (const int*)d_in[4];     // [B,G]
    const int*   nobj = (const int*)d_in[5];     // [B]
    float* out = (float*)d_out;

    char* ws = (char*)d_ws;
    size_t off = 0;
    float* pminc  = (float*)(ws + off); off += (size_t)B_ * G_ * PCH * 4;
    int*   passig = (int*)  (ws + off); off += (size_t)B_ * G_ * PCH * 4;
    float* img    = (float*)(ws + off); off += (size_t)B_ * 4 * 4;
    int*   cnt    = (int*)  (ws + off); off += 64;

    k_cost_min<<<dim3(NTILE * PCH * B_), 64, 0, stream>>>(pbox, plog, gbox, glbl,
                                                          nobj, pminc, passig, cnt);
    k_losses<<<dim3(B_), LT, 0, stream>>>(obj, pbox, plog, gbox, glbl, nobj,
                                          pminc, passig, img, cnt, out);
}

// Round 22
// 61.071 us; speedup vs baseline: 1.2795x; 1.0192x over previous
//
#include <hip/hip_runtime.h>
#include <math.h>

namespace {
constexpr int B_ = 32, P_ = 8192, G_ = 150, C_ = 8;
constexpr int TG = 10;                 // gts per block in cost kernel
constexpr int NTILE = G_ / TG;         // 15
constexpr int PCH = 16;                // P chunks in cost kernel
constexpr int PCHUNK = P_ / PCH;       // 512
constexpr int NXCD = 8;                // XCDs on MI355X
constexpr int LT = 512;                // k_losses block size (8 waves)
constexpr float ALPHA_ = 0.25f;
constexpr float THRESH_ = 1.5f;
constexpr float EPS_ = 1e-6f;
constexpr float LOG2E_ = 1.44269504088896340736f;
constexpr float LN2_   = 0.69314718055994530942f;
constexpr float HSQ2_ = 0.70710678118654752440f;   // 0.5*sqrt(2)
}

__device__ __forceinline__ float rcp_f(float x) { return __builtin_amdgcn_rcpf(x); }
__device__ __forceinline__ float rfl_f(float x) {
    return __int_as_float(__builtin_amdgcn_readfirstlane(__float_as_int(x)));
}
__device__ __forceinline__ float log_f(float x) {   // natural log via v_log
    return __builtin_amdgcn_logf(x) * LN2_;
}

// precise giou for the loss terms (matches reference op order)
__device__ __forceinline__ float giou_f(const float4 b1, const float4 b2) {
    float a1 = (b1.z - b1.x) * (b1.w - b1.y);
    float a2 = (b2.z - b2.x) * (b2.w - b2.y);
    float iw = fmaxf(fminf(b1.z, b2.z) - fmaxf(b1.x, b2.x), 0.0f);
    float ih = fmaxf(fminf(b1.w, b2.w) - fmaxf(b1.y, b2.y), 0.0f);
    float inter = iw * ih;
    float uni = a1 + a2 - inter;
    float iou = inter / (uni + EPS_);
    float enc = (fmaxf(b1.z, b2.z) - fminf(b1.x, b2.x)) *
                (fmaxf(b1.w, b2.w) - fminf(b1.y, b2.y));
    return iou - (enc - uni) / (enc + EPS_);
}

// ---------------------------------------------------------------------------
// fused 4-value block sum for LT=512 threads (one barrier)
// ---------------------------------------------------------------------------
__device__ __forceinline__ float4 block_sum4(float4 v, const int tid) {
    __shared__ float tmp[LT / 64][4];
    for (int o = 32; o; o >>= 1) {
        v.x += __shfl_down(v.x, o, 64);
        v.y += __shfl_down(v.y, o, 64);
        v.z += __shfl_down(v.z, o, 64);
        v.w += __shfl_down(v.w, o, 64);
    }
    const int wv = tid >> 6;
    if ((tid & 63) == 0) {
        tmp[wv][0] = v.x; tmp[wv][1] = v.y; tmp[wv][2] = v.z; tmp[wv][3] = v.w;
    }
    __syncthreads();
    float4 r = make_float4(0.f, 0.f, 0.f, 0.f);
#pragma unroll
    for (int i = 0; i < LT / 64; ++i) {
        r.x += tmp[i][0]; r.y += tmp[i][1]; r.z += tmp[i][2]; r.w += tmp[i][3];
    }
    return r;
}

// ---------------------------------------------------------------------------
// Kernel 1: single-wave blocks (64 threads), 1D grid, XCD-aware decode
// (R16/R18 champion body VERBATIM — frozen).  Block 0 zeroes cnt.
// ---------------------------------------------------------------------------
__global__ __launch_bounds__(64) void k_cost_min(
    const float* __restrict__ pbox,   // [B,P,4]
    const float* __restrict__ plog,   // [B,P,C]
    const float* __restrict__ gbox,   // [B,G,4]
    const int*   __restrict__ glbl,   // [B,G]
    const int*   __restrict__ nobj,   // [B]
    float* __restrict__ out_minc,     // [B,G,PCH]
    int*   __restrict__ out_assig,    // [B,G,PCH]
    int*   __restrict__ cnt)
{
    if (blockIdx.x == 0 && threadIdx.x == 0) *cnt = 0;

    // decode: bid = xcd + NXCD*(tile + NTILE*grp); pair = xcd + NXCD*grp
    const int bid  = blockIdx.x;
    const int xcd  = bid & (NXCD - 1);
    const int t2   = bid >> 3;            // NXCD == 8
    const int tile = t2 % NTILE;
    const int grp  = t2 / NTILE;
    const int pair = xcd + NXCD * grp;    // 0 .. PCH*B-1
    const int ch   = pair & (PCH - 1);    // PCH == 16
    const int b    = pair >> 4;
    const int g0   = tile * TG;
    if (g0 >= nobj[b]) return;        // dead gt-tile: results never consumed

    const int tid = threadIdx.x;      // 0..63 (one wave)
    const int p0  = ch * PCHUNK;

    __shared__ float sw[64][9];       // per-thread premultiplied -0.5*probs

    // wave-uniform gt fields -> SGPRs
    float gx1[TG], gy1[TG], gx2[TG], gy2[TG], gcx[TG], gcy[TG], gar[TG];
    int gL[TG];
    {
        const float4* gb4 = (const float4*)(gbox + ((size_t)b * G_ + g0) * 4);
        const int* gl = glbl + b * G_ + g0;
#pragma unroll
        for (int j = 0; j < TG; ++j) {
            const float4 gb = gb4[j];
            gx1[j] = rfl_f(gb.x); gy1[j] = rfl_f(gb.y);
            gx2[j] = rfl_f(gb.z); gy2[j] = rfl_f(gb.w);
            gcx[j] = rfl_f((gb.x + gb.z) * HSQ2_);
            gcy[j] = rfl_f((gb.y + gb.w) * HSQ2_);
            gar[j] = rfl_f((gb.z - gb.x) * (gb.w - gb.y));
            gL[j]  = __builtin_amdgcn_readfirstlane(gl[j]);
        }
    }

    float bc[TG]; int bi[TG];
#pragma unroll
    for (int j = 0; j < TG; ++j) { bc[j] = INFINITY; bi[j] = 0; }

    const float4* pb4 = (const float4*)(pbox + (size_t)b * P_ * 4);
    const float4* pl4 = (const float4*)(plog + (size_t)b * P_ * C_);

    for (int p = p0 + tid; p < p0 + PCHUNK; p += 64) {
        const float4 pb = pb4[p];
        const float4 l0 = pl4[2 * p];
        const float4 l1 = pl4[2 * p + 1];
        const float pcx = (pb.x + pb.z) * HSQ2_;
        const float pcy = (pb.y + pb.w) * HSQ2_;
        const float a1  = (pb.z - pb.x) * (pb.w - pb.y);

        const float m = fmaxf(fmaxf(fmaxf(l0.x, l0.y), fmaxf(l0.z, l0.w)),
                              fmaxf(fmaxf(l1.x, l1.y), fmaxf(l1.z, l1.w)));
        const float mm = -m * LOG2E_;
        const float e0 = __builtin_amdgcn_exp2f(fmaf(l0.x, LOG2E_, mm));
        const float e1 = __builtin_amdgcn_exp2f(fmaf(l0.y, LOG2E_, mm));
        const float e2 = __builtin_amdgcn_exp2f(fmaf(l0.z, LOG2E_, mm));
        const float e3 = __builtin_amdgcn_exp2f(fmaf(l0.w, LOG2E_, mm));
        const float e4 = __builtin_amdgcn_exp2f(fmaf(l1.x, LOG2E_, mm));
        const float e5 = __builtin_amdgcn_exp2f(fmaf(l1.y, LOG2E_, mm));
        const float e6 = __builtin_amdgcn_exp2f(fmaf(l1.z, LOG2E_, mm));
        const float e7 = __builtin_amdgcn_exp2f(fmaf(l1.w, LOG2E_, mm));
        const float se = ((e0 + e1) + (e2 + e3)) + ((e4 + e5) + (e6 + e7));
        const float s  = -0.5f * rcp_f(se);     // fold COST_W_CLS and the minus
        sw[tid][0] = e0 * s; sw[tid][1] = e1 * s; sw[tid][2] = e2 * s; sw[tid][3] = e3 * s;
        sw[tid][4] = e4 * s; sw[tid][5] = e5 * s; sw[tid][6] = e6 * s; sw[tid][7] = e7 * s;

#pragma unroll
        for (int j = 0; j < TG; ++j) {
            // distance: centers pre-scaled by sqrt2 -> sqrt(d2) == 2*nd
            const float dx = pcx - gcx[j], dy = pcy - gcy[j];
            const float d2 = fmaf(dx, dx, dy * dy);
            const float sd = __builtin_amdgcn_sqrtf(d2);

            const float iwr = fminf(pb.z, gx2[j]) - fmaxf(pb.x, gx1[j]);
            const float ihr = fminf(pb.w, gy2[j]) - fmaxf(pb.y, gy1[j]);
            const float inter = fmaxf(iwr, 0.0f) * fmaxf(ihr, 0.0f);
            const float uni = (a1 + gar[j]) - inter;
            const float encw = (fmaxf(pb.z, gx2[j]) - fminf(pb.x, gx1[j]));
            const float ench = (fmaxf(pb.w, gy2[j]) - fminf(pb.y, gy1[j]));
            const float enc  = encw * ench;
            // c0 = (enc-uni)/(enc+EPS) - inter/(uni+EPS), with a single rcp:
            const float x = uni + EPS_;
            const float y = enc + EPS_;
            const float r = rcp_f(x * y);
            const float num = fmaf(enc - uni, x, -(inter * y));
            const float c0 = num * r;
            const float cost = sd + (c0 + sw[tid][gL[j]]);
            // strict < keeps first (lowest p) on ties; p increases per thread
            if (cost < bc[j]) { bc[j] = cost; bi[j] = p; }
        }
    }

    // wave reduce: min cost, tie -> lowest pred index; lane 0 stores
#pragma unroll
    for (int j = 0; j < TG; ++j) {
        float c = bc[j]; int i = bi[j];
        for (int off = 32; off; off >>= 1) {
            const float c2 = __shfl_down(c, off, 64);
            const int   i2 = __shfl_down(i, off, 64);
            if (c2 < c || (c2 == c && i2 < i)) { c = c2; i = i2; }
        }
        if (tid == 0) {
            out_minc[(b * G_ + g0 + j) * PCH + ch]  = c;
            out_assig[(b * G_ + g0 + j) * PCH + ch] = i;
        }
    }
}

// ---------------------------------------------------------------------------
// Kernel 2: per-image tail, 32 blocks x 512 threads (8 waves).
//  * chunk-merge parallelized 600-way (150 gts x 4 slices, dead gts skipped;
//    slice-ascending == chunk-ascending -> identical tie-breaks)
//  * winner detection 8-way; compaction via bitmask+popcount
//  * focal fused (float4); single fused 4-value reduction
//  * final combine vectorized over one wave
// ---------------------------------------------------------------------------
__global__ __launch_bounds__(LT) void k_losses(
    const float* __restrict__ obj,    // [B,P]
    const float* __restrict__ pbox,   // [B,P,4]
    const float* __restrict__ plog,   // [B,P,C]
    const float* __restrict__ gbox,   // [B,G,4]
    const int*   __restrict__ glbl,   // [B,G]
    const int*   __restrict__ nobj,   // [B]
    const float* __restrict__ pminc,  // [B,G,PCH]
    const int*   __restrict__ passig, // [B,G,PCH]
    float* __restrict__ img,          // [B,4]: obj, bbox, class, n_m
    int* __restrict__ cnt,
    float* __restrict__ out)          // [4]
{
    const int b = blockIdx.x, tid = threadIdx.x;
    __shared__ float s_mc[G_][4];     // per-slice partial min
    __shared__ int   s_mi[G_][4];
    __shared__ float s_c[G_];
    __shared__ int   s_p[G_];
    __shared__ unsigned char s_valid[G_], s_beat[G_];
    __shared__ unsigned int s_winm[5];
    __shared__ int s_wp[G_], s_wg[G_], s_nw;
    __shared__ int s_last;

    const int n = nobj[b];
    if (tid < 5) s_winm[tid] = 0;
    if (tid < G_) s_beat[tid] = 0;

    // merge phase 1: (g, slice) 600-way; slice covers chunks 4s..4s+3
    for (int t = tid; t < G_ * 4; t += LT) {
        const int g  = t >> 2;
        if (g >= n) continue;                 // dead gt: never consumed
        const int sl = t & 3;
        const float* pc = pminc  + (size_t)(b * G_ + g) * PCH + sl * 4;
        const int*   pi = passig + (size_t)(b * G_ + g) * PCH + sl * 4;
        float c = INFINITY; int i = 0x7fffffff;
#pragma unroll
        for (int k = 0; k < 4; ++k) {         // ascending chunk
            const float c2 = pc[k]; const int i2 = pi[k];
            if (c2 < c || (c2 == c && i2 < i)) { c = c2; i = i2; }
        }
        s_mc[g][sl] = c; s_mi[g][sl] = i;
    }
    __syncthreads();

    // merge phase 2: combine 4 slices ascending (== full ascending-chunk scan)
    if (tid < G_) {
        unsigned char v = 0;
        if (tid < n) {
            float c = INFINITY; int i = 0x7fffffff;
#pragma unroll
            for (int sl = 0; sl < 4; ++sl) {
                const float c2 = s_mc[tid][sl]; const int i2 = s_mi[tid][sl];
                if (c2 < c || (c2 == c && i2 < i)) { c = c2; i = i2; }
            }
            s_c[tid] = c;
            s_p[tid] = i;
            v = (c < THRESH_);
        }
        s_valid[tid] = v;
    }
    __syncthreads();

    // winner detection, 8 slices of g2 per g:
    for (int t = tid; t < G_ * 8; t += LT) {
        const int g  = t >> 3;
        const int sl = t & 7;
        if (!s_valid[g]) continue;
        const int p = s_p[g]; const float c = s_c[g];
        const int g2e = min(sl * 19 + 19, G_);
        for (int g2 = sl * 19; g2 < g2e; ++g2) {
            if (g2 == g || !s_valid[g2] || s_p[g2] != p) continue;
            const float c2 = s_c[g2];
            if (c2 < c || (c2 == c && g2 < g)) { s_beat[g] = 1; break; }
        }
    }
    __syncthreads();

    // winner bitmask
    if (tid < G_) {
        if (s_valid[tid] && !s_beat[tid])
            atomicOr(&s_winm[tid >> 5], 1u << (tid & 31));
    }
    __syncthreads();

    // count + compaction via popcount (ascending-g slot order preserved)
    if (tid == 0) {
        int nw = 0;
#pragma unroll
        for (int w2 = 0; w2 < 5; ++w2) nw += __popc(s_winm[w2]);
        s_nw = nw;
    }
    if (tid < G_ && s_valid[tid] && !s_beat[tid]) {
        const int word = tid >> 5, bit = tid & 31;
        int slot = __popc(s_winm[word] & ((1u << bit) - 1));
#pragma unroll
        for (int w2 = 0; w2 < 4; ++w2)
            if (w2 < word) slot += __popc(s_winm[w2]);
        s_wp[slot] = s_p[tid];
        s_wg[slot] = tid;
    }
    __syncthreads();
    const int nw = s_nw;

    // focal objectness: full background sum, float4-vectorized
    const float* ob = obj + (size_t)b * P_;
    const float4* ob4 = (const float4*)ob;
    float fsum = 0.0f;
#pragma unroll
    for (int k = 0; k < P_ / (LT * 4); ++k) {
        const float4 v4 = ob4[tid + k * LT];
        const float vs[4] = {v4.x, v4.y, v4.z, v4.w};
#pragma unroll
        for (int u = 0; u < 4; ++u) {
            float v = fminf(fmaxf(vs[u], 1e-7f), 1.0f - 1e-7f);
            fsum += ALPHA_ * v * v * (-log_f(1.0f - v));
        }
    }

    float gsum = 0.0f, asum = 0.0f, csum = 0.0f;
    if (tid < nw) {
        const int p = s_wp[tid], g = s_wg[tid];
        float v = ob[p];
        v = fminf(fmaxf(v, 1e-7f), 1.0f - 1e-7f);
        const float nl1 = -log_f(1.0f - v);                 // matches bg term
        fsum += ALPHA_ * (1.0f - v) * (1.0f - v) * (-log_f(v))
              - ALPHA_ * v * v * nl1;

        const float4 pb = *(const float4*)(pbox + ((size_t)b * P_ + p) * 4);
        const float4 gb = *(const float4*)(gbox + ((size_t)b * G_ + g) * 4);
        gsum = 1.0f - giou_f(pb, gb);

        const float pa = (pb.z - pb.x) / (pb.w - pb.y + EPS_);
        const float ga = (gb.z - gb.x) / (gb.w - gb.y + EPS_);
        const float da = fabsf(pa - ga);
        asum = (da < 1.0f) ? 0.5f * da * da : (da - 0.5f);

        const float* lg = plog + ((size_t)b * P_ + p) * C_;
        const float l0 = lg[0], l1 = lg[1], l2 = lg[2], l3 = lg[3];
        const float l4 = lg[4], l5 = lg[5], l6 = lg[6], l7 = lg[7];
        const float m = fmaxf(fmaxf(fmaxf(l0, l1), fmaxf(l2, l3)),
                              fmaxf(fmaxf(l4, l5), fmaxf(l6, l7)));
        const float se = expf(l0 - m) + expf(l1 - m) + expf(l2 - m) + expf(l3 - m)
                       + expf(l4 - m) + expf(l5 - m) + expf(l6 - m) + expf(l7 - m);
        const int L = glbl[b * G_ + g];
        const float lL = lg[L];
        csum = -(lL - m - log_f(se));
    }

    const float4 tot = block_sum4(make_float4(fsum, gsum, asum, csum), tid);

    if (tid == 0) {
        const float denom = fmaxf((float)nw, 1.0f);
        img[b * 4 + 0] = tot.x / (float)P_;              // obj_loss (mean)
        img[b * 4 + 1] = tot.y / denom + tot.z / denom;  // giou + aspect
        img[b * 4 + 2] = tot.w / denom;                  // class
        img[b * 4 + 3] = (float)nw;                      // n_m
        __threadfence();
        const int old = atomicAdd(cnt, 1);
        s_last = (old == B_ - 1);
    }
    __syncthreads();
    if (s_last && tid < 64) {
        __threadfence();
        // one wave: lane t<32 loads img[t] as float4, shuffle-sum
        float4 v = (tid < B_) ? ((const float4*)img)[tid]
                              : make_float4(0.f, 0.f, 0.f, 0.f);
        for (int o = 32; o; o >>= 1) {
            v.x += __shfl_down(v.x, o, 64);
            v.y += __shfl_down(v.y, o, 64);
            v.z += __shfl_down(v.z, o, 64);
            v.w += __shfl_down(v.w, o, 64);
        }
        if (tid == 0) {
            const float denom = fmaxf(v.w, 1.0f);
            const float o  = v.x / (float)B_;
            const float bb = v.y / denom;
            const float cl = v.z / denom;
            out[0] = o + bb + cl;
            out[1] = o;
            out[2] = bb;
            out[3] = cl;
            *cnt = 0;
        }
    }
}

extern "C" void kernel_launch(void* const* d_in, const int* in_sizes, int n_in,
                              void* d_out, int out_size, void* d_ws, size_t ws_size,
                              hipStream_t stream) {
    const float* obj  = (const float*)d_in[0];   // [B,P]
    const float* pbox = (const float*)d_in[1];   // [B,P,4]
    const float* plog = (const float*)d_in[2];   // [B,P,C]
    const float* gbox = (const float*)d_in[3];   // [B,G,4]
    const int*   glbl = (const int*)d_in[4];     // [B,G]
    const int*   nobj = (const int*)d_in[5];     // [B]
    float* out = (float*)d_out;

    char* ws = (char*)d_ws;
    size_t off = 0;
    float* pminc  = (float*)(ws + off); off += (size_t)B_ * G_ * PCH * 4;
    int*   passig = (int*)  (ws + off); off += (size_t)B_ * G_ * PCH * 4;
    float* img    = (float*)(ws + off); off += (size_t)B_ * 4 * 4;
    int*   cnt    = (int*)  (ws + off); off += 64;

    k_cost_min<<<dim3(NTILE * PCH * B_), 64, 0, stream>>>(pbox, plog, gbox, glbl,
                                                          nobj, pminc, passig, cnt);
    k_losses<<<dim3(B_), LT, 0, stream>>>(obj, pbox, plog, gbox, glbl, nobj,
                                          pminc, passig, img, cnt, out);
}